// Round 12
// baseline (2258.346 us; speedup 1.0000x reference)
//
#include <hip/hip_runtime.h>
#include <cmath>

#define NB 4
#define TT 2048
#define DD 256
#define NH 4
#define BT (NB*TT)   // 8192 rows

static constexpr float DT_ = 0.25f;

typedef _Float16 f16x8 __attribute__((ext_vector_type(8)));
typedef _Float16 f16x4 __attribute__((ext_vector_type(4)));
typedef float    f32x4 __attribute__((ext_vector_type(4)));

static constexpr size_t HSZ = (size_t)NB * NH * TT * 64;   // per split Q/K array: 2M halves
static constexpr size_t FSZ = (size_t)BT * 256;            // one partial-F buffer (floats)

// ---------------- split W into fp16 hi/lo (runs once per launch) ----------------
__global__ __launch_bounds__(256)
void split_weights(const float* __restrict__ Wqk, const float* __restrict__ Wout,
                   _Float16* __restrict__ WqkH, _Float16* __restrict__ WqkL,
                   _Float16* __restrict__ WoutH, _Float16* __restrict__ WoutL)
{
    const int idx = blockIdx.x * 256 + threadIdx.x;   // float4 group index
    const float4 v = (idx < 32768) ? ((const float4*)Wqk)[idx]
                                   : ((const float4*)Wout)[idx - 32768];
    f16x4 h, l;
    h[0]=(_Float16)v.x; l[0]=(_Float16)(v.x-(float)h[0]);
    h[1]=(_Float16)v.y; l[1]=(_Float16)(v.y-(float)h[1]);
    h[2]=(_Float16)v.z; l[2]=(_Float16)(v.z-(float)h[2]);
    h[3]=(_Float16)v.w; l[3]=(_Float16)(v.w-(float)h[3]);
    if (idx < 32768) { ((f16x4*)WqkH)[idx] = h; ((f16x4*)WqkL)[idx] = l; }
    else { ((f16x4*)WoutH)[idx-32768] = h; ((f16x4*)WoutL)[idx-32768] = l; }
}

// ---------------- row-wise l2 norm over D=256; optional fp16 split emit ----------------
__global__ __launch_bounds__(256)
void l2norm_rows(const float* __restrict__ src, float* __restrict__ dst,
                 _Float16* __restrict__ dstH, _Float16* __restrict__ dstL) {
    const int wave = threadIdx.x >> 6;
    const int lane = threadIdx.x & 63;
    const size_t row = (size_t)blockIdx.x * 4 + wave;
    float4 v = ((const float4*)(src + row * DD))[lane];
    float ss = v.x*v.x + v.y*v.y + v.z*v.z + v.w*v.w;
    #pragma unroll
    for (int off = 32; off; off >>= 1) ss += __shfl_xor(ss, off, 64);
    const float inv = 1.0f / fmaxf(sqrtf(ss), 1e-12f);
    v.x *= inv; v.y *= inv; v.z *= inv; v.w *= inv;
    ((float4*)(dst + row * DD))[lane] = v;
    if (dstH != nullptr) {
        f16x4 h, l;
        h[0]=(_Float16)v.x; l[0]=(_Float16)(v.x-(float)h[0]);
        h[1]=(_Float16)v.y; l[1]=(_Float16)(v.y-(float)h[1]);
        h[2]=(_Float16)v.z; l[2]=(_Float16)(v.z-(float)h[2]);
        h[3]=(_Float16)v.w; l[3]=(_Float16)(v.w-(float)h[3]);
        ((f16x4*)(dstH + row * DD))[lane] = h;
        ((f16x4*)(dstL + row * DD))[lane] = l;
    }
}

// ---------------- split-fp16 MFMA GEMM: C = A[M,256] * W[N,256]^T ----------------
// (unchanged from R11 — passing) Block 256 thr / 4 waves; tile 128m x 64n.
__global__ __launch_bounds__(256)
void gemm_mfma(const _Float16* __restrict__ AH, const _Float16* __restrict__ AL,
               const float* __restrict__ Fp,
               const _Float16* __restrict__ BH, const _Float16* __restrict__ BL,
               const float* __restrict__ omega, const float* __restrict__ bout,
               const float* __restrict__ xin, float* __restrict__ kacc,
               _Float16* __restrict__ xsH, _Float16* __restrict__ xsL,
               float* __restrict__ xout,
               _Float16* __restrict__ Qhi, _Float16* __restrict__ Qlo,
               _Float16* __restrict__ Khi, _Float16* __restrict__ Klo,
               _Float16* __restrict__ KtrH,
               int stage)
{
    __shared__ _Float16 Ah[128 * 72];
    __shared__ _Float16 Al[128 * 72];
    __shared__ _Float16 Bh[64 * 72];
    __shared__ _Float16 Bl[64 * 72];
    const int m0 = blockIdx.x * 128, n0 = blockIdx.y * 64;
    const int t  = threadIdx.x;
    const int w  = t >> 6;
    const int l  = t & 63;
    const int lr = l & 15;
    const int lq = l >> 4;

    f32x4 acc[2][4];
    #pragma unroll
    for (int s = 0; s < 2; ++s)
        #pragma unroll
        for (int nt = 0; nt < 4; ++nt) acc[s][nt] = (f32x4){0.f,0.f,0.f,0.f};

    for (int kc = 0; kc < 4; ++kc) {
        const int k0 = kc * 64;
        __syncthreads();
        if (stage < 0) {
            #pragma unroll
            for (int s2 = 0; s2 < 4; ++s2) {
                const int idx = t + 256 * s2;
                const int r = idx >> 3, c8 = (idx & 7) * 8;
                *(uint4*)&Ah[r * 72 + c8] = *(const uint4*)(AH + (size_t)(m0 + r) * 256 + k0 + c8);
                *(uint4*)&Al[r * 72 + c8] = *(const uint4*)(AL + (size_t)(m0 + r) * 256 + k0 + c8);
            }
        } else {
            #pragma unroll
            for (int s2 = 0; s2 < 4; ++s2) {
                const int idx = t + 256 * s2;
                const int r = idx >> 3, c8 = (idx & 7) * 8;
                const size_t go = (size_t)(m0 + r) * 256 + k0 + c8;
                float sv[8] = {0,0,0,0,0,0,0,0};
                #pragma unroll
                for (int p = 0; p < 4; ++p) {
                    const float4 a0 = *(const float4*)(Fp + p*FSZ + go);
                    const float4 a1 = *(const float4*)(Fp + p*FSZ + go + 4);
                    sv[0]+=a0.x; sv[1]+=a0.y; sv[2]+=a0.z; sv[3]+=a0.w;
                    sv[4]+=a1.x; sv[5]+=a1.y; sv[6]+=a1.z; sv[7]+=a1.w;
                }
                f16x8 hv, lv;
                #pragma unroll
                for (int e = 0; e < 8; ++e) {
                    hv[e] = (_Float16)sv[e];
                    lv[e] = (_Float16)(sv[e] - (float)hv[e]);
                }
                *(f16x8*)&Ah[r * 72 + c8] = hv;
                *(f16x8*)&Al[r * 72 + c8] = lv;
            }
        }
        #pragma unroll
        for (int s2 = 0; s2 < 2; ++s2) {
            const int idx = t + 256 * s2;
            const int r = idx >> 3, c8 = (idx & 7) * 8;
            *(uint4*)&Bh[r * 72 + c8] = *(const uint4*)(BH + (size_t)(n0 + r) * 256 + k0 + c8);
            *(uint4*)&Bl[r * 72 + c8] = *(const uint4*)(BL + (size_t)(n0 + r) * 256 + k0 + c8);
        }
        __syncthreads();
        #pragma unroll
        for (int c = 0; c < 2; ++c) {
            f16x8 ah[2], al[2], bh[4], bl[4];
            #pragma unroll
            for (int s = 0; s < 2; ++s) {
                ah[s] = *(const f16x8*)&Ah[(32*w + 16*s + lr) * 72 + 32*c + 8*lq];
                al[s] = *(const f16x8*)&Al[(32*w + 16*s + lr) * 72 + 32*c + 8*lq];
            }
            #pragma unroll
            for (int nt = 0; nt < 4; ++nt) {
                bh[nt] = *(const f16x8*)&Bh[(16*nt + lr) * 72 + 32*c + 8*lq];
                bl[nt] = *(const f16x8*)&Bl[(16*nt + lr) * 72 + 32*c + 8*lq];
            }
            #pragma unroll
            for (int s = 0; s < 2; ++s)
                #pragma unroll
                for (int nt = 0; nt < 4; ++nt) {
                    acc[s][nt] = __builtin_amdgcn_mfma_f32_16x16x32_f16(ah[s], bh[nt], acc[s][nt], 0, 0, 0);
                    acc[s][nt] = __builtin_amdgcn_mfma_f32_16x16x32_f16(ah[s], bl[nt], acc[s][nt], 0, 0, 0);
                    acc[s][nt] = __builtin_amdgcn_mfma_f32_16x16x32_f16(al[s], bh[nt], acc[s][nt], 0, 0, 0);
                }
        }
    }

    if (stage < 0) {
        float ss[2][4];
        #pragma unroll
        for (int s = 0; s < 2; ++s)
            #pragma unroll
            for (int r = 0; r < 4; ++r) {
                float v = 0.f;
                #pragma unroll
                for (int nt = 0; nt < 4; ++nt) v += acc[s][nt][r] * acc[s][nt][r];
                ss[s][r] = v;
            }
        #pragma unroll
        for (int off = 1; off < 16; off <<= 1)
            #pragma unroll
            for (int s = 0; s < 2; ++s)
                #pragma unroll
                for (int r = 0; r < 4; ++r)
                    ss[s][r] += __shfl_xor(ss[s][r], off, 64);
        const int  b    = m0 >> 11;
        const int  h    = (n0 >> 6) & 3;
        const bool is_k = (n0 >= 256);
        const size_t bhi = (size_t)b * NH + h;
        _Float16* dhi = (is_k ? Khi : Qhi) + bhi * (size_t)TT * 64;
        _Float16* dlo = (is_k ? Klo : Qlo) + bhi * (size_t)TT * 64;
        const int mloc = m0 & (TT - 1);
        #pragma unroll
        for (int s = 0; s < 2; ++s) {
            const int r0 = 32*w + 16*s + 4*lq;
            float inv[4];
            #pragma unroll
            for (int r = 0; r < 4; ++r) inv[r] = 1.0f / fmaxf(sqrtf(ss[s][r]), 1e-12f);
            #pragma unroll
            for (int nt = 0; nt < 4; ++nt) {
                const int d = 16*nt + lr;
                f16x4 hv, lv;
                #pragma unroll
                for (int r = 0; r < 4; ++r) {
                    const float val = acc[s][nt][r] * inv[r];
                    hv[r] = (_Float16)val;
                    lv[r] = (_Float16)(val - (float)hv[r]);
                    dhi[(size_t)(mloc + r0 + r) * 64 + d] = hv[r];
                    dlo[(size_t)(mloc + r0 + r) * 64 + d] = lv[r];
                }
                if (is_k) {
                    const size_t tb = bhi * (size_t)64 * TT + (size_t)d * TT + mloc + r0;
                    *(f16x4*)(KtrH + tb) = hv;
                }
            }
        }
    } else {
        #pragma unroll
        for (int s = 0; s < 2; ++s) {
            const int row0 = m0 + 32*w + 16*s + 4*lq;
            #pragma unroll
            for (int nt = 0; nt < 4; ++nt) {
                const int col = n0 + 16*nt + lr;
                const float ob = omega[col] + bout[col];
                #pragma unroll
                for (int r = 0; r < 4; ++r) {
                    const size_t off = (size_t)(row0 + r) * 256 + col;
                    const float f = acc[s][nt][r] + ob;
                    if (stage == 0) {
                        kacc[off] = f;
                        const float xv = xin[off] + 0.125f * f;
                        const _Float16 xh = (_Float16)xv;
                        xsH[off] = xh;
                        xsL[off] = (_Float16)(xv - (float)xh);
                    } else if (stage < 3) {
                        kacc[off] += 2.0f * f;
                        const float c = (stage == 1) ? 0.125f : 0.25f;
                        const float xv = xin[off] + c * f;
                        const _Float16 xh = (_Float16)xv;
                        xsH[off] = xh;
                        xsL[off] = (_Float16)(xv - (float)xh);
                    } else {
                        xout[off] = xin[off] + (DT_ / 6.0f) * (kacc[off] + f);
                    }
                }
            }
        }
    }
}

// ---------------- F_partial = sin(Q K^T) K over a 512-j quarter ----------------
// R12: BARRIER-FREE j-loop. K fragments are loaded DIRECTLY from global
// (A-frag of GEMM1 = 16B contiguous at K[j0+16nt+lr][8lq..]; B-frag of GEMM2 =
// 16B at Ktr[16nt+lr][j0+8lq..]) — the 4 waves/block re-read the same 128B
// lines, so loads are L1/L2-hot. LDS holds only the per-wave P round-trip
// (no cross-wave state -> zero __syncthreads in the loop; waves self-schedule,
// eliminating the R7-R11 barrier convoy). grid (16,4,16) = 4 blocks/CU.
__global__ __launch_bounds__(256, 4)
void kuramoto_attn(const _Float16* __restrict__ Qhi, const _Float16* __restrict__ Qlo,
                   const _Float16* __restrict__ Khi, const _Float16* __restrict__ Klo,
                   const _Float16* __restrict__ KtrH,
                   float* __restrict__ Fp)
{
    __shared__ _Float16 Pw[4][16 * 68];      // per-wave sin(S) staging, one s at a time
    const int bh = blockIdx.z;                     // b*NH + h
    const int b  = bh >> 2, h = bh & 3;
    const size_t base  = (size_t)bh * TT * 64;
    const size_t tbase = (size_t)bh * 64 * TT;
    const int j00 = blockIdx.y * 512;              // this quarter's first j
    float* Fout = Fp + (size_t)blockIdx.y * FSZ;
    const int t = threadIdx.x;
    const int w = t >> 6;
    const int l = t & 63;
    const int lr = l & 15;
    const int lq = l >> 4;
    const int i0 = blockIdx.x * 128 + w * 32;

    f16x8 qh[2][2], ql[2][2];
    #pragma unroll
    for (int s = 0; s < 2; ++s) {
        const size_t qoff = base + (size_t)(i0 + 16*s + lr) * 64 + lq * 8;
        qh[s][0] = *(const f16x8*)(Qhi + qoff);
        qh[s][1] = *(const f16x8*)(Qhi + qoff + 32);
        ql[s][0] = *(const f16x8*)(Qlo + qoff);
        ql[s][1] = *(const f16x8*)(Qlo + qoff + 32);
    }

    f32x4 Facc[2][4];
    #pragma unroll
    for (int s = 0; s < 2; ++s)
        #pragma unroll
        for (int nt = 0; nt < 4; ++nt) Facc[s][nt] = (f32x4){0.f, 0.f, 0.f, 0.f};

    for (int tt = 0; tt < 8; ++tt) {
        const int j0 = j00 + tt * 64;
        // GEMM1 (swapped): S^T[j][i] = K·Q^T, 3-term split, A-frags from global
        f16x4 pv[2][4];
        #pragma unroll
        for (int nt = 0; nt < 4; ++nt) {
            const _Float16* krow = Khi + base + (size_t)(j0 + 16*nt + lr) * 64 + 8*lq;
            const _Float16* lrow = Klo + base + (size_t)(j0 + 16*nt + lr) * 64 + 8*lq;
            f16x8 kh0 = *(const f16x8*)(krow);
            f16x8 kh1 = *(const f16x8*)(krow + 32);
            f16x8 kl0 = *(const f16x8*)(lrow);
            f16x8 kl1 = *(const f16x8*)(lrow + 32);
            #pragma unroll
            for (int s = 0; s < 2; ++s) {
                f32x4 a = (f32x4){0.f, 0.f, 0.f, 0.f};
                a = __builtin_amdgcn_mfma_f32_16x16x32_f16(kh0, qh[s][0], a, 0, 0, 0);
                a = __builtin_amdgcn_mfma_f32_16x16x32_f16(kh1, qh[s][1], a, 0, 0, 0);
                a = __builtin_amdgcn_mfma_f32_16x16x32_f16(kl0, qh[s][0], a, 0, 0, 0);
                a = __builtin_amdgcn_mfma_f32_16x16x32_f16(kl1, qh[s][1], a, 0, 0, 0);
                a = __builtin_amdgcn_mfma_f32_16x16x32_f16(kh0, ql[s][0], a, 0, 0, 0);
                a = __builtin_amdgcn_mfma_f32_16x16x32_f16(kh1, ql[s][1], a, 0, 0, 0);
                #pragma unroll
                for (int r = 0; r < 4; ++r) pv[s][nt][r] = (_Float16)__sinf(a[r]);
            }
        }
        // GEMM2 B-frags from global (hoisted across both s-subtiles)
        f16x8 kd0[4], kd1[4];
        #pragma unroll
        for (int nt = 0; nt < 4; ++nt) {
            const _Float16* drow = KtrH + tbase + (size_t)(16*nt + lr) * TT + j0 + 8*lq;
            kd0[nt] = *(const f16x8*)(drow);
            kd1[nt] = *(const f16x8*)(drow + 32);
        }
        // P round trip + GEMM2, s-sequential through one per-wave buffer
        #pragma unroll
        for (int s = 0; s < 2; ++s) {
            #pragma unroll
            for (int nt = 0; nt < 4; ++nt)
                *(f16x4*)&Pw[w][lr * 68 + 16*nt + 4*lq] = pv[s][nt];
            f16x8 ph0 = *(const f16x8*)&Pw[w][lr * 68 + lq * 8];
            f16x8 ph1 = *(const f16x8*)&Pw[w][lr * 68 + 32 + lq * 8];
            #pragma unroll
            for (int nt = 0; nt < 4; ++nt) {
                Facc[s][nt] = __builtin_amdgcn_mfma_f32_16x16x32_f16(ph0, kd0[nt], Facc[s][nt], 0, 0, 0);
                Facc[s][nt] = __builtin_amdgcn_mfma_f32_16x16x32_f16(ph1, kd1[nt], Facc[s][nt], 0, 0, 0);
            }
        }
    }
    // write partial F fp32: row = i0 + 16s + 4lq + r, col = h*64 + 16nt + lr
    #pragma unroll
    for (int s = 0; s < 2; ++s) {
        float* fo = Fout + ((size_t)b * TT + i0 + 16*s + 4*lq) * 256 + h * 64 + lr;
        #pragma unroll
        for (int nt = 0; nt < 4; ++nt)
            #pragma unroll
            for (int r = 0; r < 4; ++r)
                fo[(size_t)r * 256 + nt * 16] = Facc[s][nt][r];
    }
}

extern "C" void kernel_launch(void* const* d_in, const int* in_sizes, int n_in,
                              void* d_out, int out_size, void* d_ws, size_t ws_size,
                              hipStream_t stream) {
    const float* z     = (const float*)d_in[0];
    const float* omega = (const float*)d_in[1];
    const float* Wqk   = (const float*)d_in[2];
    const float* Wout  = (const float*)d_in[3];
    const float* bout  = (const float*)d_in[4];

    float* x    = (float*)d_ws;                  // [BT,256] fp32 state
    float* kacc = x + FSZ;                       // [BT,256] fp32 RK4 accumulator
    float* Fp   = kacc + FSZ;                    // [4][BT,256] fp32 partial forces
    _Float16* xsH  = (_Float16*)(Fp + 4 * FSZ);
    _Float16* xsL  = xsH  + FSZ;
    _Float16* Qhi  = xsL  + FSZ;
    _Float16* Qlo  = Qhi  + HSZ;
    _Float16* Khi  = Qlo  + HSZ;
    _Float16* Klo  = Khi  + HSZ;
    _Float16* KtrH = Klo  + HSZ;
    _Float16* WqkH = KtrH + HSZ;
    _Float16* WqkL = WqkH + (size_t)512 * 256;
    _Float16* WoutH= WqkL + (size_t)512 * 256;
    _Float16* WoutL= WoutH + (size_t)256 * 256;

    split_weights<<<192, 256, 0, stream>>>(Wqk, Wout, WqkH, WqkL, WoutH, WoutL);

    for (int step = 0; step < 4; ++step) {
        l2norm_rows<<<BT / 4, 256, 0, stream>>>(step == 0 ? z : x, x, xsH, xsL);
        for (int s = 0; s < 4; ++s) {
            gemm_mfma<<<dim3(BT / 128, 8), 256, 0, stream>>>(
                xsH, xsL, nullptr, WqkH, WqkL,
                nullptr, nullptr, nullptr, nullptr, nullptr, nullptr, nullptr,
                Qhi, Qlo, Khi, Klo, KtrH, -1);
            kuramoto_attn<<<dim3(TT / 128, 4, NB * NH), 256, 0, stream>>>(
                Qhi, Qlo, Khi, Klo, KtrH, Fp);
            gemm_mfma<<<dim3(BT / 128, 4), 256, 0, stream>>>(
                nullptr, nullptr, Fp, WoutH, WoutL,
                omega, bout, x, kacc, xsH, xsL, x,
                nullptr, nullptr, nullptr, nullptr, nullptr, s);
        }
    }
    l2norm_rows<<<BT / 4, 256, 0, stream>>>(x, (float*)d_out, nullptr, nullptr);
}

// Round 13
// 1195.553 us; speedup vs baseline: 1.8890x; 1.8890x over previous
//
#include <hip/hip_runtime.h>
#include <cmath>

#define NB 4
#define TT 2048
#define DD 256
#define NH 4
#define BT (NB*TT)   // 8192 rows

static constexpr float DT_ = 0.25f;

typedef _Float16 f16x8 __attribute__((ext_vector_type(8)));
typedef _Float16 f16x4 __attribute__((ext_vector_type(4)));
typedef float    f32x4 __attribute__((ext_vector_type(4)));

static constexpr size_t HSZ = (size_t)NB * NH * TT * 64;   // per split Q/K array: 2M halves
static constexpr size_t FSZ = (size_t)BT * 256;            // one partial-F buffer (floats)

// ---------------- split W into fp16 hi/lo (runs once per launch) ----------------
__global__ __launch_bounds__(256)
void split_weights(const float* __restrict__ Wqk, const float* __restrict__ Wout,
                   _Float16* __restrict__ WqkH, _Float16* __restrict__ WqkL,
                   _Float16* __restrict__ WoutH, _Float16* __restrict__ WoutL)
{
    const int idx = blockIdx.x * 256 + threadIdx.x;   // float4 group index
    const float4 v = (idx < 32768) ? ((const float4*)Wqk)[idx]
                                   : ((const float4*)Wout)[idx - 32768];
    f16x4 h, l;
    h[0]=(_Float16)v.x; l[0]=(_Float16)(v.x-(float)h[0]);
    h[1]=(_Float16)v.y; l[1]=(_Float16)(v.y-(float)h[1]);
    h[2]=(_Float16)v.z; l[2]=(_Float16)(v.z-(float)h[2]);
    h[3]=(_Float16)v.w; l[3]=(_Float16)(v.w-(float)h[3]);
    if (idx < 32768) { ((f16x4*)WqkH)[idx] = h; ((f16x4*)WqkL)[idx] = l; }
    else { ((f16x4*)WoutH)[idx-32768] = h; ((f16x4*)WoutL)[idx-32768] = l; }
}

// ---------------- Wcomb = Wqk @ Wout  [512,256], split fp16; qkob = (omega+bout)@Wqk^T ----
__global__ __launch_bounds__(256)
void comb_weights(const float* __restrict__ Wqk, const float* __restrict__ Wout,
                  const float* __restrict__ omega, const float* __restrict__ bout,
                  _Float16* __restrict__ WcombH, _Float16* __restrict__ WcombL,
                  float* __restrict__ qkob)
{
    __shared__ float qrow[256];
    __shared__ float pr[256];
    const int n = blockIdx.x;      // 512 blocks
    const int k = threadIdx.x;
    qrow[k] = Wqk[n * 256 + k];
    __syncthreads();
    float s = 0.f;
    for (int m = 0; m < 256; ++m) s = fmaf(qrow[m], Wout[m * 256 + k], s);
    const _Float16 h = (_Float16)s;
    WcombH[n * 256 + k] = h;
    WcombL[n * 256 + k] = (_Float16)(s - (float)h);
    pr[k] = (omega[k] + bout[k]) * qrow[k];
    __syncthreads();
    if (k == 0) {
        float t = 0.f;
        for (int i = 0; i < 256; ++i) t += pr[i];
        qkob[n] = t;
    }
}

// ---------------- row-wise l2 norm over D=256; optional fp16 split emit ----------------
__global__ __launch_bounds__(256)
void l2norm_rows(const float* __restrict__ src, float* __restrict__ dst,
                 _Float16* __restrict__ dstH, _Float16* __restrict__ dstL) {
    const int wave = threadIdx.x >> 6;
    const int lane = threadIdx.x & 63;
    const size_t row = (size_t)blockIdx.x * 4 + wave;
    float4 v = ((const float4*)(src + row * DD))[lane];
    float ss = v.x*v.x + v.y*v.y + v.z*v.z + v.w*v.w;
    #pragma unroll
    for (int off = 32; off; off >>= 1) ss += __shfl_xor(ss, off, 64);
    const float inv = 1.0f / fmaxf(sqrtf(ss), 1e-12f);
    v.x *= inv; v.y *= inv; v.z *= inv; v.w *= inv;
    ((float4*)(dst + row * DD))[lane] = v;
    if (dstH != nullptr) {
        f16x4 h, l;
        h[0]=(_Float16)v.x; l[0]=(_Float16)(v.x-(float)h[0]);
        h[1]=(_Float16)v.y; l[1]=(_Float16)(v.y-(float)h[1]);
        h[2]=(_Float16)v.z; l[2]=(_Float16)(v.z-(float)h[2]);
        h[3]=(_Float16)v.w; l[3]=(_Float16)(v.w-(float)h[3]);
        ((f16x4*)(dstH + row * DD))[lane] = h;
        ((f16x4*)(dstL + row * DD))[lane] = l;
    }
}

// ---------------- split-fp16 MFMA GEMM, 128m x 64n tile, 3 modes ----------------
// mode 0: qk = x@Wqk^T. A = xsH/xsL; stores raw acc to qkx fp32; headnorm-emits Q/K/Ktr.
// mode 1: force->qk. A = sum of 3 Fp partials (split in staging; blockIdx.y==0 also
//         accumulates wfac*sum into Facc); B = Wcomb; epilogue
//         val = qkx + cc*(acc + qkob) -> headnorm-emit.
// mode 2: final x update. A = Facc + sum of 3 Fp partials; B = Wout;
//         epilogue xout = xin + DT/6*acc + DT*(omega+bout).
__global__ __launch_bounds__(256)
void gemm_mfma(const _Float16* __restrict__ AH, const _Float16* __restrict__ AL,
               const float* __restrict__ Fp, float* __restrict__ Facc,
               const _Float16* __restrict__ BH, const _Float16* __restrict__ BL,
               float* __restrict__ qkx, const float* __restrict__ qkob,
               const float* __restrict__ omega, const float* __restrict__ bout,
               const float* __restrict__ xin, float* __restrict__ xout,
               _Float16* __restrict__ Qhi, _Float16* __restrict__ Qlo,
               _Float16* __restrict__ Khi, _Float16* __restrict__ Klo,
               _Float16* __restrict__ KtrH,
               int mode, float cc, int faccm)
{
    __shared__ _Float16 Ah[128 * 72];
    __shared__ _Float16 Al[128 * 72];
    __shared__ _Float16 Bh[64 * 72];
    __shared__ _Float16 Bl[64 * 72];
    const int m0 = blockIdx.x * 128, n0 = blockIdx.y * 64;
    const int t  = threadIdx.x;
    const int w  = t >> 6;
    const int l  = t & 63;
    const int lr = l & 15;
    const int lq = l >> 4;

    f32x4 acc[2][4];
    #pragma unroll
    for (int s = 0; s < 2; ++s)
        #pragma unroll
        for (int nt = 0; nt < 4; ++nt) acc[s][nt] = (f32x4){0.f,0.f,0.f,0.f};

    for (int kc = 0; kc < 4; ++kc) {
        const int k0 = kc * 64;
        __syncthreads();
        if (mode == 0) {
            #pragma unroll
            for (int s2 = 0; s2 < 4; ++s2) {
                const int idx = t + 256 * s2;
                const int r = idx >> 3, c8 = (idx & 7) * 8;
                *(uint4*)&Ah[r * 72 + c8] = *(const uint4*)(AH + (size_t)(m0 + r) * 256 + k0 + c8);
                *(uint4*)&Al[r * 72 + c8] = *(const uint4*)(AL + (size_t)(m0 + r) * 256 + k0 + c8);
            }
        } else {
            #pragma unroll
            for (int s2 = 0; s2 < 4; ++s2) {
                const int idx = t + 256 * s2;
                const int r = idx >> 3, c8 = (idx & 7) * 8;
                const size_t go = (size_t)(m0 + r) * 256 + k0 + c8;
                float sv[8] = {0,0,0,0,0,0,0,0};
                if (mode == 2) {
                    const float4 a0 = *(const float4*)(Facc + go);
                    const float4 a1 = *(const float4*)(Facc + go + 4);
                    sv[0]=a0.x; sv[1]=a0.y; sv[2]=a0.z; sv[3]=a0.w;
                    sv[4]=a1.x; sv[5]=a1.y; sv[6]=a1.z; sv[7]=a1.w;
                }
                #pragma unroll
                for (int p = 0; p < 3; ++p) {
                    const float4 a0 = *(const float4*)(Fp + p*FSZ + go);
                    const float4 a1 = *(const float4*)(Fp + p*FSZ + go + 4);
                    sv[0]+=a0.x; sv[1]+=a0.y; sv[2]+=a0.z; sv[3]+=a0.w;
                    sv[4]+=a1.x; sv[5]+=a1.y; sv[6]+=a1.z; sv[7]+=a1.w;
                }
                if (mode == 1 && blockIdx.y == 0) {
                    if (faccm == 1) {
                        *(float4*)(Facc + go)     = make_float4(sv[0], sv[1], sv[2], sv[3]);
                        *(float4*)(Facc + go + 4) = make_float4(sv[4], sv[5], sv[6], sv[7]);
                    } else {
                        float4 f0 = *(const float4*)(Facc + go);
                        float4 f1 = *(const float4*)(Facc + go + 4);
                        f0.x += 2.f*sv[0]; f0.y += 2.f*sv[1]; f0.z += 2.f*sv[2]; f0.w += 2.f*sv[3];
                        f1.x += 2.f*sv[4]; f1.y += 2.f*sv[5]; f1.z += 2.f*sv[6]; f1.w += 2.f*sv[7];
                        *(float4*)(Facc + go)     = f0;
                        *(float4*)(Facc + go + 4) = f1;
                    }
                }
                f16x8 hv, lv;
                #pragma unroll
                for (int e = 0; e < 8; ++e) {
                    hv[e] = (_Float16)sv[e];
                    lv[e] = (_Float16)(sv[e] - (float)hv[e]);
                }
                *(f16x8*)&Ah[r * 72 + c8] = hv;
                *(f16x8*)&Al[r * 72 + c8] = lv;
            }
        }
        #pragma unroll
        for (int s2 = 0; s2 < 2; ++s2) {
            const int idx = t + 256 * s2;
            const int r = idx >> 3, c8 = (idx & 7) * 8;
            *(uint4*)&Bh[r * 72 + c8] = *(const uint4*)(BH + (size_t)(n0 + r) * 256 + k0 + c8);
            *(uint4*)&Bl[r * 72 + c8] = *(const uint4*)(BL + (size_t)(n0 + r) * 256 + k0 + c8);
        }
        __syncthreads();
        #pragma unroll
        for (int c = 0; c < 2; ++c) {
            f16x8 ah[2], al[2], bh[4], bl[4];
            #pragma unroll
            for (int s = 0; s < 2; ++s) {
                ah[s] = *(const f16x8*)&Ah[(32*w + 16*s + lr) * 72 + 32*c + 8*lq];
                al[s] = *(const f16x8*)&Al[(32*w + 16*s + lr) * 72 + 32*c + 8*lq];
            }
            #pragma unroll
            for (int nt = 0; nt < 4; ++nt) {
                bh[nt] = *(const f16x8*)&Bh[(16*nt + lr) * 72 + 32*c + 8*lq];
                bl[nt] = *(const f16x8*)&Bl[(16*nt + lr) * 72 + 32*c + 8*lq];
            }
            #pragma unroll
            for (int s = 0; s < 2; ++s)
                #pragma unroll
                for (int nt = 0; nt < 4; ++nt) {
                    acc[s][nt] = __builtin_amdgcn_mfma_f32_16x16x32_f16(ah[s], bh[nt], acc[s][nt], 0, 0, 0);
                    acc[s][nt] = __builtin_amdgcn_mfma_f32_16x16x32_f16(ah[s], bl[nt], acc[s][nt], 0, 0, 0);
                    acc[s][nt] = __builtin_amdgcn_mfma_f32_16x16x32_f16(al[s], bh[nt], acc[s][nt], 0, 0, 0);
                }
        }
    }

    if (mode == 2) {
        #pragma unroll
        for (int s = 0; s < 2; ++s) {
            const int row0 = m0 + 32*w + 16*s + 4*lq;
            #pragma unroll
            for (int nt = 0; nt < 4; ++nt) {
                const int col = n0 + 16*nt + lr;
                const float ob = omega[col] + bout[col];
                #pragma unroll
                for (int r = 0; r < 4; ++r) {
                    const size_t off = (size_t)(row0 + r) * 256 + col;
                    xout[off] = xin[off] + (DT_ / 6.0f) * acc[s][nt][r] + DT_ * ob;
                }
            }
        }
    } else {
        // val = mode0 ? acc : qkx + cc*(acc + qkob); mode0 stores raw acc to qkx
        float val[2][4][4];
        #pragma unroll
        for (int s = 0; s < 2; ++s) {
            const int row0 = m0 + 32*w + 16*s + 4*lq;
            #pragma unroll
            for (int nt = 0; nt < 4; ++nt) {
                const int col = n0 + 16*nt + lr;
                #pragma unroll
                for (int r = 0; r < 4; ++r) {
                    const size_t qo = (size_t)(row0 + r) * 512 + col;
                    if (mode == 0) {
                        val[s][nt][r] = acc[s][nt][r];
                        qkx[qo] = acc[s][nt][r];
                    } else {
                        val[s][nt][r] = qkx[qo] + cc * (acc[s][nt][r] + qkob[col]);
                    }
                }
            }
        }
        float ss[2][4];
        #pragma unroll
        for (int s = 0; s < 2; ++s)
            #pragma unroll
            for (int r = 0; r < 4; ++r) {
                float v = 0.f;
                #pragma unroll
                for (int nt = 0; nt < 4; ++nt) v += val[s][nt][r] * val[s][nt][r];
                ss[s][r] = v;
            }
        #pragma unroll
        for (int off = 1; off < 16; off <<= 1)
            #pragma unroll
            for (int s = 0; s < 2; ++s)
                #pragma unroll
                for (int r = 0; r < 4; ++r)
                    ss[s][r] += __shfl_xor(ss[s][r], off, 64);
        const int  b    = m0 >> 11;
        const int  h    = (n0 >> 6) & 3;
        const bool is_k = (n0 >= 256);
        const size_t bhi = (size_t)b * NH + h;
        _Float16* dhi = (is_k ? Khi : Qhi) + bhi * (size_t)TT * 64;
        _Float16* dlo = (is_k ? Klo : Qlo) + bhi * (size_t)TT * 64;
        const int mloc = m0 & (TT - 1);
        #pragma unroll
        for (int s = 0; s < 2; ++s) {
            const int r0 = 32*w + 16*s + 4*lq;
            float inv[4];
            #pragma unroll
            for (int r = 0; r < 4; ++r) inv[r] = 1.0f / fmaxf(sqrtf(ss[s][r]), 1e-12f);
            #pragma unroll
            for (int nt = 0; nt < 4; ++nt) {
                const int d = 16*nt + lr;
                f16x4 hv, lv;
                #pragma unroll
                for (int r = 0; r < 4; ++r) {
                    const float v2 = val[s][nt][r] * inv[r];
                    hv[r] = (_Float16)v2;
                    lv[r] = (_Float16)(v2 - (float)hv[r]);
                    dhi[(size_t)(mloc + r0 + r) * 64 + d] = hv[r];
                    dlo[(size_t)(mloc + r0 + r) * 64 + d] = lv[r];
                }
                if (is_k) {
                    const size_t tb = bhi * (size_t)64 * TT + (size_t)d * TT + mloc + r0;
                    *(f16x4*)(KtrH + tb) = hv;
                }
            }
        }
    }
}

// ---------------- F_partial = sin(Q K^T) K over a j third (R9 verbatim — 44 us) ------
__global__ __launch_bounds__(256, 3)
void kuramoto_attn(const _Float16* __restrict__ Qhi, const _Float16* __restrict__ Qlo,
                   const _Float16* __restrict__ Khi, const _Float16* __restrict__ Klo,
                   const _Float16* __restrict__ KtrH,
                   float* __restrict__ Fp)
{
    __shared__ _Float16 KjH[64 * 72];
    __shared__ _Float16 KjL[64 * 72];
    __shared__ _Float16 KdH[64 * 72];
    __shared__ _Float16 Pw[4][2][16 * 68];
    const int bh = blockIdx.z;
    const int b  = bh >> 2, h = bh & 3;
    const size_t base  = (size_t)bh * TT * 64;
    const size_t tbase = (size_t)bh * 64 * TT;
    const int t0 = blockIdx.y * 11;
    const int tn = (blockIdx.y == 2) ? 10 : 11;
    float* Fout = Fp + (size_t)blockIdx.y * FSZ;
    const int t = threadIdx.x;
    const int w = t >> 6;
    const int l = t & 63;
    const int lr = l & 15;
    const int lq = l >> 4;
    const int i0 = blockIdx.x * 128 + w * 32;

    f16x8 qh[2][2], ql[2][2];
    #pragma unroll
    for (int s = 0; s < 2; ++s) {
        const size_t qoff = base + (size_t)(i0 + 16*s + lr) * 64 + lq * 8;
        qh[s][0] = *(const f16x8*)(Qhi + qoff);
        qh[s][1] = *(const f16x8*)(Qhi + qoff + 32);
        ql[s][0] = *(const f16x8*)(Qlo + qoff);
        ql[s][1] = *(const f16x8*)(Qlo + qoff + 32);
    }

    f32x4 Facc[2][4];
    #pragma unroll
    for (int s = 0; s < 2; ++s)
        #pragma unroll
        for (int nt = 0; nt < 4; ++nt) Facc[s][nt] = (f32x4){0.f, 0.f, 0.f, 0.f};

    const int sr = t >> 3;
    const int so = (t & 7) * 8;

    for (int tt = 0; tt < tn; ++tt) {
        const int j0 = (t0 + tt) * 64;
        __syncthreads();
        {
            *(uint4*)&KjH[sr * 72 + so]        = *(const uint4*)(Khi + base + (size_t)(j0 + sr) * 64 + so);
            *(uint4*)&KjH[(sr + 32) * 72 + so] = *(const uint4*)(Khi + base + (size_t)(j0 + sr + 32) * 64 + so);
            *(uint4*)&KjL[sr * 72 + so]        = *(const uint4*)(Klo + base + (size_t)(j0 + sr) * 64 + so);
            *(uint4*)&KjL[(sr + 32) * 72 + so] = *(const uint4*)(Klo + base + (size_t)(j0 + sr + 32) * 64 + so);
            *(uint4*)&KdH[sr * 72 + so]        = *(const uint4*)(KtrH + tbase + (size_t)sr * TT + j0 + so);
            *(uint4*)&KdH[(sr + 32) * 72 + so] = *(const uint4*)(KtrH + tbase + (size_t)(sr + 32) * TT + j0 + so);
        }
        __syncthreads();
        #pragma unroll
        for (int nt = 0; nt < 4; ++nt) {
            f16x8 kh0 = *(const f16x8*)&KjH[(16*nt + lr) * 72 + lq * 8];
            f16x8 kh1 = *(const f16x8*)&KjH[(16*nt + lr) * 72 + 32 + lq * 8];
            f16x8 kl0 = *(const f16x8*)&KjL[(16*nt + lr) * 72 + lq * 8];
            f16x8 kl1 = *(const f16x8*)&KjL[(16*nt + lr) * 72 + 32 + lq * 8];
            #pragma unroll
            for (int s = 0; s < 2; ++s) {
                f32x4 a = (f32x4){0.f, 0.f, 0.f, 0.f};
                a = __builtin_amdgcn_mfma_f32_16x16x32_f16(kh0, qh[s][0], a, 0, 0, 0);
                a = __builtin_amdgcn_mfma_f32_16x16x32_f16(kh1, qh[s][1], a, 0, 0, 0);
                a = __builtin_amdgcn_mfma_f32_16x16x32_f16(kl0, qh[s][0], a, 0, 0, 0);
                a = __builtin_amdgcn_mfma_f32_16x16x32_f16(kl1, qh[s][1], a, 0, 0, 0);
                a = __builtin_amdgcn_mfma_f32_16x16x32_f16(kh0, ql[s][0], a, 0, 0, 0);
                a = __builtin_amdgcn_mfma_f32_16x16x32_f16(kh1, ql[s][1], a, 0, 0, 0);
                f16x4 pv;
                #pragma unroll
                for (int r = 0; r < 4; ++r) pv[r] = (_Float16)__sinf(a[r]);
                *(f16x4*)&Pw[w][s][lr * 68 + 16*nt + 4*lq] = pv;
            }
        }
        f16x8 ph[2][2];
        #pragma unroll
        for (int s = 0; s < 2; ++s) {
            ph[s][0] = *(const f16x8*)&Pw[w][s][lr * 68 + lq * 8];
            ph[s][1] = *(const f16x8*)&Pw[w][s][lr * 68 + 32 + lq * 8];
        }
        #pragma unroll
        for (int nt = 0; nt < 4; ++nt) {
            f16x8 kh0 = *(const f16x8*)&KdH[(16*nt + lr) * 72 + lq * 8];
            f16x8 kh1 = *(const f16x8*)&KdH[(16*nt + lr) * 72 + 32 + lq * 8];
            #pragma unroll
            for (int s = 0; s < 2; ++s) {
                Facc[s][nt] = __builtin_amdgcn_mfma_f32_16x16x32_f16(ph[s][0], kh0, Facc[s][nt], 0, 0, 0);
                Facc[s][nt] = __builtin_amdgcn_mfma_f32_16x16x32_f16(ph[s][1], kh1, Facc[s][nt], 0, 0, 0);
            }
        }
    }
    #pragma unroll
    for (int s = 0; s < 2; ++s) {
        float* fo = Fout + ((size_t)b * TT + i0 + 16*s + 4*lq) * 256 + h * 64 + lr;
        #pragma unroll
        for (int nt = 0; nt < 4; ++nt)
            #pragma unroll
            for (int r = 0; r < 4; ++r)
                fo[(size_t)r * 256 + nt * 16] = Facc[s][nt][r];
    }
}

extern "C" void kernel_launch(void* const* d_in, const int* in_sizes, int n_in,
                              void* d_out, int out_size, void* d_ws, size_t ws_size,
                              hipStream_t stream) {
    const float* z     = (const float*)d_in[0];
    const float* omega = (const float*)d_in[1];
    const float* Wqk   = (const float*)d_in[2];
    const float* Wout  = (const float*)d_in[3];
    const float* bout  = (const float*)d_in[4];

    float* x    = (float*)d_ws;                  // [BT,256] fp32 state
    float* Facc = x + FSZ;                       // [BT,256] weighted force accumulator
    float* Fp   = Facc + FSZ;                    // [3][BT,256] fp32 partial forces
    float* qkx  = Fp + 3 * FSZ;                  // [BT,512] raw qk of step-start x
    float* qkob = qkx + (size_t)BT * 512;        // [512]
    _Float16* xsH  = (_Float16*)(qkob + 512);
    _Float16* xsL  = xsH  + FSZ;
    _Float16* Qhi  = xsL  + FSZ;
    _Float16* Qlo  = Qhi  + HSZ;
    _Float16* Khi  = Qlo  + HSZ;
    _Float16* Klo  = Khi  + HSZ;
    _Float16* KtrH = Klo  + HSZ;
    _Float16* WqkH = KtrH + HSZ;
    _Float16* WqkL = WqkH + (size_t)512 * 256;
    _Float16* WoutH= WqkL + (size_t)512 * 256;
    _Float16* WoutL= WoutH + (size_t)256 * 256;
    _Float16* WcombH = WoutL + (size_t)256 * 256;   // [512,256]
    _Float16* WcombL = WcombH + (size_t)512 * 256;

    split_weights<<<192, 256, 0, stream>>>(Wqk, Wout, WqkH, WqkL, WoutH, WoutL);
    comb_weights<<<512, 256, 0, stream>>>(Wqk, Wout, omega, bout, WcombH, WcombL, qkob);

    for (int step = 0; step < 4; ++step) {
        l2norm_rows<<<BT / 4, 256, 0, stream>>>(step == 0 ? z : x, x, xsH, xsL);
        // stage 0: qk = x@Wqk^T (stores qkx + emits Q/K)
        gemm_mfma<<<dim3(BT / 128, 8), 256, 0, stream>>>(
            xsH, xsL, nullptr, nullptr, WqkH, WqkL, qkx, nullptr,
            nullptr, nullptr, nullptr, nullptr,
            Qhi, Qlo, Khi, Klo, KtrH, 0, 0.f, 0);
        kuramoto_attn<<<dim3(TT / 128, 3, NB * NH), 256, 0, stream>>>(
            Qhi, Qlo, Khi, Klo, KtrH, Fp);
        // stages 1..3: qk_s = qkx + c_s*(F_{s-1}@Wcomb + qkob); Facc += w*F
        for (int s = 1; s <= 3; ++s) {
            const float cs = (s == 3) ? 0.25f : 0.125f;
            gemm_mfma<<<dim3(BT / 128, 8), 256, 0, stream>>>(
                nullptr, nullptr, Fp, Facc, WcombH, WcombL, qkx, qkob,
                nullptr, nullptr, nullptr, nullptr,
                Qhi, Qlo, Khi, Klo, KtrH, 1, cs, (s == 1) ? 1 : 2);
            kuramoto_attn<<<dim3(TT / 128, 3, NB * NH), 256, 0, stream>>>(
                Qhi, Qlo, Khi, Klo, KtrH, Fp);
        }
        // final: x += DT/6 * (Facc + F3)@Wout^T + DT*(omega+bout)
        gemm_mfma<<<dim3(BT / 128, 4), 256, 0, stream>>>(
            nullptr, nullptr, Fp, Facc, WoutH, WoutL, nullptr, nullptr,
            omega, bout, x, x,
            nullptr, nullptr, nullptr, nullptr, nullptr, 2, 0.f, 0);
    }
    l2norm_rows<<<BT / 4, 256, 0, stream>>>(x, (float*)d_out, nullptr, nullptr);
}